// Round 4
// baseline (1233.805 us; speedup 1.0000x reference)
//
#include <hip/hip_runtime.h>
#include <stdint.h>

// Problem constants
#define TT 64
#define BB 32
#define VV 32000
#define EE 512
#define HH 512
#define G4 2048   // 4*H

// Dtypes: tokens int32; ALL other inputs f32; OUTPUT f32 (reference dtype).
// (Round-3 forensics: reading inputs as bf16 -> NaN, so inputs are f32.
//  Rounds 1-2 failed only because output was written as packed bf16.)

typedef float f32x4 __attribute__((ext_vector_type(4)));
typedef short bf16x8 __attribute__((ext_vector_type(8)));

__device__ __forceinline__ unsigned int f2bf(float f) {
    union { float f; uint32_t u; } v; v.f = f;
    uint32_t r = v.u + 0x7fffu + ((v.u >> 16) & 1u);
    return (r >> 16);
}
__device__ __forceinline__ float bf2f(unsigned int u) {
    union { uint32_t u; float f; } v; v.u = u << 16; return v.f;
}

// ---------------------------------------------------------------------------
// prep: gather X = emb[tok] -> bf16, copy h0/c0 into f32 state buffers
// ---------------------------------------------------------------------------
__global__ __launch_bounds__(256)
void prep_kernel(const float* __restrict__ emb, const int* __restrict__ tokens,
                 const float* __restrict__ h0, const float* __restrict__ c0,
                 unsigned short* __restrict__ Xbf, float* __restrict__ h,
                 float* __restrict__ c) {
    const int NX = TT * BB * EE / 4;   // 262,144
    const int NH = BB * HH / 4;        // 4,096
    int i = blockIdx.x * 256 + threadIdx.x;
    if (i < NX) {
        int r = i >> 7;            // row = t*32+b
        int e4 = i & 127;
        int tok = tokens[r];
        float4 v = ((const float4*)(emb + (size_t)tok * EE))[e4];
        uint2 o;
        o.x = f2bf(v.x) | (f2bf(v.y) << 16);
        o.y = f2bf(v.z) | (f2bf(v.w) << 16);
        *(uint2*)(Xbf + (size_t)r * EE + e4 * 4) = o;
        return;
    }
    i -= NX;
    if (i < NH) { ((float4*)h)[i] = ((const float4*)h0)[i]; return; }
    i -= NH;
    if (i < NH) { ((float4*)c)[i] = ((const float4*)c0)[i]; return; }
}

// ---------------------------------------------------------------------------
// GEMM: C[M,N](f32) = A[M,K](bf16) @ B[N,K](f32, converted in staging)^T
//       + bias1[n] (+ bias2[n]).  128x128 tile, BK=64, 4 waves (2x2 of 64x64).
// Register staging into padded LDS (row stride 68 shorts -> 2-way bank
// aliasing on ds_read_b64, free per m136).
// ---------------------------------------------------------------------------
#define LDA 68   // LDS row stride in shorts (64 data + 4 pad), rows 8B-aligned

__global__ __launch_bounds__(256, 2)
void gemm_bt(const unsigned short* __restrict__ A, const float* __restrict__ Bm,
             float* __restrict__ Cout, const float* __restrict__ bias1,
             const float* __restrict__ bias2, int N, int K) {
    __shared__ unsigned short lA[128 * LDA];
    __shared__ unsigned short lB[128 * LDA];
    const int tid = threadIdx.x;
    const int lane = tid & 63;
    const int w = tid >> 6;
    const int m0 = blockIdx.y * 128;
    const int n0 = blockIdx.x * 128;
    const int wm = (w & 1) * 64;
    const int wn = (w >> 1) * 64;
    f32x4 acc[4][4];
#pragma unroll
    for (int i = 0; i < 4; ++i)
#pragma unroll
        for (int j = 0; j < 4; ++j) acc[i][j] = (f32x4){0.f, 0.f, 0.f, 0.f};

    for (int k0 = 0; k0 < K; k0 += 64) {
#pragma unroll
        for (int i = 0; i < 4; ++i) {
            int c = tid + 256 * i;       // chunk id: 1024 chunks of 8 elements
            int row = c >> 3;            // tile row [0,128)
            int kg = c & 7;              // k-group [0,8)
            // A: bf16, one 16B load
            uint4 va = *(const uint4*)(A + (size_t)(m0 + row) * K + k0 + kg * 8);
            *(uint2*)&lA[row * LDA + kg * 8]     = make_uint2(va.x, va.y);
            *(uint2*)&lA[row * LDA + kg * 8 + 4] = make_uint2(va.z, va.w);
            // B: f32, two 16B loads, convert to bf16
            const float4* bp = (const float4*)(Bm + (size_t)(n0 + row) * K + k0 + kg * 8);
            float4 b0 = bp[0], b1 = bp[1];
            uint2 p0, p1;
            p0.x = f2bf(b0.x) | (f2bf(b0.y) << 16);
            p0.y = f2bf(b0.z) | (f2bf(b0.w) << 16);
            p1.x = f2bf(b1.x) | (f2bf(b1.y) << 16);
            p1.y = f2bf(b1.z) | (f2bf(b1.w) << 16);
            *(uint2*)&lB[row * LDA + kg * 8]     = p0;
            *(uint2*)&lB[row * LDA + kg * 8 + 4] = p1;
        }
        __syncthreads();
#pragma unroll
        for (int ks = 0; ks < 2; ++ks) {
            const int kgrp = ks * 4 + (lane >> 4);   // A[m=lane&15][k=quad*8+j]
            bf16x8 af[4], bfr[4];
#pragma unroll
            for (int mi = 0; mi < 4; ++mi) {
                int row = wm + mi * 16 + (lane & 15);
                union { uint2 d[2]; bf16x8 v; } u;
                u.d[0] = *(const uint2*)&lA[row * LDA + kgrp * 8];
                u.d[1] = *(const uint2*)&lA[row * LDA + kgrp * 8 + 4];
                af[mi] = u.v;
            }
#pragma unroll
            for (int ni = 0; ni < 4; ++ni) {
                int row = wn + ni * 16 + (lane & 15);
                union { uint2 d[2]; bf16x8 v; } u;
                u.d[0] = *(const uint2*)&lB[row * LDA + kgrp * 8];
                u.d[1] = *(const uint2*)&lB[row * LDA + kgrp * 8 + 4];
                bfr[ni] = u.v;
            }
#pragma unroll
            for (int mi = 0; mi < 4; ++mi)
#pragma unroll
                for (int ni = 0; ni < 4; ++ni)
                    acc[mi][ni] = __builtin_amdgcn_mfma_f32_16x16x32_bf16(
                        af[mi], bfr[ni], acc[mi][ni], 0, 0, 0);
        }
        __syncthreads();
    }
    // epilogue: D layout col=lane&15 (n), row=(lane>>4)*4+reg (m); f32 store
    const int col_l = lane & 15;
    const int row_l = (lane >> 4) * 4;
#pragma unroll
    for (int ni = 0; ni < 4; ++ni) {
        int col = n0 + wn + ni * 16 + col_l;
        float bv = bias1[col];
        if (bias2) bv += bias2[col];
#pragma unroll
        for (int mi = 0; mi < 4; ++mi) {
            int rowb = m0 + wm + mi * 16 + row_l;
#pragma unroll
            for (int r = 0; r < 4; ++r) {
                Cout[(size_t)(rowb + r) * N + col] = acc[mi][ni][r] + bv;
            }
        }
    }
}

// ---------------------------------------------------------------------------
// step: gates = XG[t] + h_in @ W_hh^T ; LSTM cell ; masked h/c update.
// 256 blocks x 256 thr. Thread = (b=tid&31, jsel=(tid>>5)&1, kq=tid>>6);
// column jh = blockIdx.x*2 + jsel, k-range [kq*128, kq*128+128).
// h staged transposed bf16 in LDS; W_hh f32 rows shared by 32 lanes (L2
// broadcast). h double-buffered across launches.
// ---------------------------------------------------------------------------
__global__ __launch_bounds__(256)
void step_kernel(const float* __restrict__ XG, const float* __restrict__ Whh,
                 const int* __restrict__ tokens, const float* __restrict__ hin,
                 float* __restrict__ hout, float* __restrict__ cS,
                 unsigned short* __restrict__ Htmp, int t) {
    __shared__ unsigned short hT[512 * 33];   // hT[k*33 + b]
    __shared__ float part[256 * 4];
    const int tid = threadIdx.x;
    const int b = tid & 31;
    const int jsel = (tid >> 5) & 1;
    const int kq = tid >> 6;
    const int jh = blockIdx.x * 2 + jsel;

    for (int u = tid; u < BB * HH; u += 256) {
        hT[(u & 511) * 33 + (u >> 9)] = (unsigned short)f2bf(hin[u]);
    }
    __syncthreads();

    const float* w0 = Whh + (size_t)(0 * HH + jh) * HH;
    const float* w1 = Whh + (size_t)(1 * HH + jh) * HH;
    const float* w2 = Whh + (size_t)(2 * HH + jh) * HH;
    const float* w3 = Whh + (size_t)(3 * HH + jh) * HH;
    float a0 = 0.f, a1 = 0.f, a2 = 0.f, a3 = 0.f;
    const int kbase = kq * 128;
#pragma unroll 4
    for (int k4 = 0; k4 < 32; ++k4) {
        int k = kbase + k4 * 4;
        float4 W0 = *(const float4*)(w0 + k);
        float4 W1 = *(const float4*)(w1 + k);
        float4 W2 = *(const float4*)(w2 + k);
        float4 W3 = *(const float4*)(w3 + k);
        float h0v = bf2f(hT[(k + 0) * 33 + b]);
        float h1v = bf2f(hT[(k + 1) * 33 + b]);
        float h2v = bf2f(hT[(k + 2) * 33 + b]);
        float h3v = bf2f(hT[(k + 3) * 33 + b]);
        a0 += h0v * W0.x + h1v * W0.y + h2v * W0.z + h3v * W0.w;
        a1 += h0v * W1.x + h1v * W1.y + h2v * W1.z + h3v * W1.w;
        a2 += h0v * W2.x + h1v * W2.y + h2v * W2.z + h3v * W2.w;
        a3 += h0v * W3.x + h1v * W3.y + h2v * W3.z + h3v * W3.w;
    }
    *(float4*)&part[tid * 4] = make_float4(a0, a1, a2, a3);
    __syncthreads();

    if (tid < 64) {
        int b2 = tid & 31, js2 = tid >> 5;
        int jh2 = blockIdx.x * 2 + js2;
        float g[4];
#pragma unroll
        for (int gg = 0; gg < 4; ++gg) {
            float s = 0.f;
#pragma unroll
            for (int q = 0; q < 4; ++q) s += part[(q * 64 + js2 * 32 + b2) * 4 + gg];
            g[gg] = s + XG[((size_t)t * BB + b2) * G4 + gg * HH + jh2];
        }
        float ig = 1.f / (1.f + __expf(-g[0]));
        float fg = 1.f / (1.f + __expf(-g[1]));
        float gt = tanhf(g[2]);
        float og = 1.f / (1.f + __expf(-g[3]));
        float c_old = cS[b2 * HH + jh2];
        float c_tmp = fg * c_old + ig * gt;
        float h_tmp = og * tanhf(c_tmp);
        bool msk = tokens[t * BB + b2] != 0;   // PAD == 0
        cS[b2 * HH + jh2] = msk ? c_tmp : c_old;
        float h_old = hin[b2 * HH + jh2];
        hout[b2 * HH + jh2] = msk ? h_tmp : h_old;
        Htmp[((size_t)t * BB + b2) * HH + jh2] = (unsigned short)f2bf(h_tmp);
    }
}

// ---------------------------------------------------------------------------
extern "C" void kernel_launch(void* const* d_in, const int* in_sizes, int n_in,
                              void* d_out, int out_size, void* d_ws, size_t ws_size,
                              hipStream_t stream) {
    const int*   tokens = (const int*)d_in[0];
    const float* emb    = (const float*)d_in[1];
    const float* W_ih   = (const float*)d_in[2];
    const float* W_hh   = (const float*)d_in[3];
    const float* b_ih   = (const float*)d_in[4];
    const float* b_hh   = (const float*)d_in[5];
    const float* W_fc   = (const float*)d_in[6];
    const float* b_fc   = (const float*)d_in[7];
    const float* h0     = (const float*)d_in[8];
    const float* c0     = (const float*)d_in[9];

    char* ws = (char*)d_ws;
    size_t o = 0;
    unsigned short* Xbf  = (unsigned short*)(ws + o); o += (size_t)TT * BB * EE * 2;  //  2.10 MB
    unsigned short* Htmp = (unsigned short*)(ws + o); o += (size_t)TT * BB * HH * 2;  //  2.10 MB
    float* XG = (float*)(ws + o); o += (size_t)TT * BB * G4 * 4;                      // 16.78 MB
    float* hA = (float*)(ws + o); o += (size_t)BB * HH * 4;
    float* hB = (float*)(ws + o); o += (size_t)BB * HH * 4;
    float* cS = (float*)(ws + o); o += (size_t)BB * HH * 4;
    (void)ws_size; (void)in_sizes; (void)n_in; (void)out_size;

    // 1) gather X, init state
    prep_kernel<<<1056, 256, 0, stream>>>(emb, tokens, h0, c0, Xbf, hA, cS);
    // 2) XG = X @ W_ih^T + b_ih + b_hh   (M=2048, N=2048, K=512, f32 out)
    dim3 gx(G4 / 128, (TT * BB) / 128);
    gemm_bt<<<gx, 256, 0, stream>>>(Xbf, W_ih, XG, b_ih, b_hh, G4, EE);
    // 3) recurrence, 64 sequential launches, h double-buffered
    for (int t = 0; t < TT; ++t) {
        const float* hin = (t & 1) ? hB : hA;
        float* hout = (t & 1) ? hA : hB;
        step_kernel<<<256, 256, 0, stream>>>(XG, W_hh, tokens, hin, hout, cS, Htmp, t);
    }
    // 4) logits = Htmp @ W_fc^T + b_fc   (M=2048, N=32000, K=512, f32 out)
    dim3 gp(VV / 128, (TT * BB) / 128);
    gemm_bt<<<gp, 256, 0, stream>>>(Htmp, W_fc, (float*)d_out, b_fc, nullptr, VV, HH);
}